// Round 8
// baseline (1455.250 us; speedup 1.0000x reference)
//
#include <hip/hip_runtime.h>
#include <stdint.h>

#define N_ACTIVE 200000
#define N_IN 64
#define N_OUT 64
#define K_FILT 27
#define R_PAIRS 100000
#define TOTP (K_FILT * R_PAIRS)          // 2,700,000
#define RB 128                           // output rows per block
#define NB ((N_ACTIVE + RB - 1) / RB)    // 1563
#define NBUCK (NB * K_FILT)              // 42,201
#define NSB ((NBUCK + 255) / 256)        // 165
#define ELDS 2304                        // staged entries/block (mean 1728, +13 sigma)

#define CF_BLOCKS (N_ACTIVE * N_IN / 8 / 256)    // 6250
#define CW_BLOCKS K_FILT
#define HI_BLOCKS ((TOTP + 255) / 256)

typedef __bf16 bf16x8 __attribute__((ext_vector_type(8)));
typedef float f32x4 __attribute__((ext_vector_type(4)));

__device__ __forceinline__ void gll16(const void* g, void* l) {
    __builtin_amdgcn_global_load_lds(
        (const __attribute__((address_space(1))) void*)g,
        (__attribute__((address_space(3))) void*)l, 16, 0, 0);
}

__global__ __launch_bounds__(256) void zero_ints(int* __restrict__ p, int n) {
    int i = blockIdx.x * 256 + threadIdx.x;
    if (i < n) p[i] = 0;
}

// ---------------------------------------------------------------------------
// fused prep: convert_feat | convert_wt | hist
// ---------------------------------------------------------------------------
__global__ __launch_bounds__(256) void prep_fused(
    const float* __restrict__ feat, __bf16* __restrict__ featb,
    const float* __restrict__ wsrc, __bf16* __restrict__ wt,
    const int* __restrict__ out_idx, int* __restrict__ cnt)
{
    int bb = blockIdx.x, t = threadIdx.x;
    if (bb < CF_BLOCKS) {
        int i = bb * 256 + t;
        const f32x4* src = reinterpret_cast<const f32x4*>(feat) + 2 * (size_t)i;
        f32x4 v0 = __builtin_nontemporal_load(src);
        f32x4 v1 = __builtin_nontemporal_load(src + 1);
        bf16x8 o;
        o[0] = (__bf16)v0[0]; o[1] = (__bf16)v0[1]; o[2] = (__bf16)v0[2]; o[3] = (__bf16)v0[3];
        o[4] = (__bf16)v1[0]; o[5] = (__bf16)v1[1]; o[6] = (__bf16)v1[2]; o[7] = (__bf16)v1[3];
        reinterpret_cast<bf16x8*>(featb)[i] = o;
    } else if (bb < CF_BLOCKS + CW_BLOCKS) {
        int kf = bb - CF_BLOCKS;
        const float* wk = wsrc + kf * 4096;
        __bf16* wo = wt + kf * 4096;
        int o = t >> 2, i0 = (t & 3) * 16;
        bf16x8 a, b;
        #pragma unroll
        for (int j = 0; j < 8; ++j) a[j] = (__bf16)wk[(i0 + j) * 64 + o];
        #pragma unroll
        for (int j = 0; j < 8; ++j) b[j] = (__bf16)wk[(i0 + 8 + j) * 64 + o];
        *reinterpret_cast<bf16x8*>(wo + o * 64 + i0) = a;
        *reinterpret_cast<bf16x8*>(wo + o * 64 + i0 + 8) = b;
    } else {
        int p = (bb - CF_BLOCKS - CW_BLOCKS) * 256 + t;
        if (p < TOTP) {
            unsigned k = (unsigned)p / (unsigned)R_PAIRS;
            int b = (out_idx[p] >> 7) * K_FILT + (int)k;
            atomicAdd(&cnt[b], 1);
        }
    }
}

// ---- hierarchical exclusive scan over NBUCK counters ----
__global__ __launch_bounds__(256) void scan1(const int* __restrict__ cnt,
                                             int* __restrict__ off,
                                             int* __restrict__ bsum) {
    __shared__ int s[256];
    int t = threadIdx.x, i = blockIdx.x * 256 + t;
    int v = (i < NBUCK) ? cnt[i] : 0;
    s[t] = v;
    __syncthreads();
    #pragma unroll
    for (int d = 1; d < 256; d <<= 1) {
        int x = (t >= d) ? s[t - d] : 0;
        __syncthreads();
        s[t] += x;
        __syncthreads();
    }
    if (i < NBUCK) off[i] = s[t] - v;
    if (t == 255) bsum[blockIdx.x] = s[255];
}

__global__ __launch_bounds__(256) void scan2(int* __restrict__ bsum) {
    __shared__ int s[256];
    int t = threadIdx.x;
    int v = (t < NSB) ? bsum[t] : 0;
    s[t] = v;
    __syncthreads();
    #pragma unroll
    for (int d = 1; d < 256; d <<= 1) {
        int x = (t >= d) ? s[t - d] : 0;
        __syncthreads();
        s[t] += x;
        __syncthreads();
    }
    if (t < NSB) bsum[t] = s[t] - v;
}

__global__ __launch_bounds__(256) void scan3(int* __restrict__ off,
                                             const int* __restrict__ bsum,
                                             int* __restrict__ cursor) {
    int t = threadIdx.x, i = blockIdx.x * 256 + t;
    if (i < NBUCK) {
        int v = off[i] + bsum[blockIdx.x];
        off[i] = v;
        cursor[i] = v;
    }
    if (i == 0) off[NBUCK] = TOTP;
}

// ---------------------------------------------------------------------------
// scatter pair -> bucket list; entry packed as (in_row << 7) | out_local
// ---------------------------------------------------------------------------
__global__ __launch_bounds__(256) void scatter_pack(const int* __restrict__ in_idx,
                                                    const int* __restrict__ out_idx,
                                                    int* __restrict__ cursor,
                                                    int* __restrict__ entries) {
    int p = blockIdx.x * 256 + threadIdx.x;
    if (p >= TOTP) return;
    unsigned k = (unsigned)p / (unsigned)R_PAIRS;
    int orow = out_idx[p];
    int iv = __builtin_nontemporal_load(&in_idx[p]);
    int rg = orow >> 7;
    int bkt = rg * K_FILT + (int)k;
    int pos = atomicAdd(&cursor[bkt], 1);
    entries[pos] = (iv << 7) | (orow & 127);
}

// ---------------------------------------------------------------------------
// conv: block (512 thr) owns 128 out rows. Per (kf,chunk) step: async-stage
// NEXT bucket's gathered rows into LDS via global_load_lds (per-lane gather
// source, granule-XOR pre-swizzle), while computing the CURRENT bucket from
// the other buffer. One barrier per step = the dbuf handoff (its vmcnt(0)
// drain lands a full compute-phase after issue). MFMA layouts as r3 (verified):
// A row=lane&15,k=(lane>>4)*8; C/D col=lane&15,row=(lane>>4)*4+reg.
// ---------------------------------------------------------------------------
__global__ __launch_bounds__(512) void conv_fused(
    const __bf16* __restrict__ featb,   // [N_ACTIVE][64] bf16
    const __bf16* __restrict__ wtb,     // [K][o][i] bf16 transposed
    const float* __restrict__ bias,
    const int* __restrict__ off,        // [NBUCK+1]
    const int* __restrict__ entries,    // [TOTP] packed
    float* __restrict__ out)            // [N_ACTIVE][64] fp32
{
    __shared__ float outT[RB][68];      // 34,816 B
    __shared__ char  Abuf[2][16384];    // 32,768 B: [buf][row<128][granule<8][16B]
    __shared__ int   eLds[ELDS];        //  9,216 B
    __shared__ int   sOff[K_FILT + 1];
    __shared__ int   descS[96];
    __shared__ int   nSsh;

    const int b = blockIdx.x;
    const int t = threadIdx.x;
    const int w = t >> 6;               // wave 0..7
    const int lane = t & 63;
    const int lrow = lane & 15;
    const int g0   = lane >> 4;         // a0 granule index
    const int rg4  = g0 * 4;
    const int swz  = lane & 7;
    const int bK = b * K_FILT;

    if (t < K_FILT + 1) sOff[t] = off[bK + t];
    {   // zero out tile
        f32x4 z = {0.f, 0.f, 0.f, 0.f};
        f32x4* o4 = reinterpret_cast<f32x4*>(&outT[0][0]);
        for (int j = t; j < RB * 68 / 4; j += 512) o4[j] = z;
    }
    __syncthreads();

    const int blockStart = sOff[0];
    const int total = sOff[K_FILT] - blockStart;
    const int stged = total < ELDS ? total : ELDS;
    for (int i = t; i < stged; i += 512)
        eLds[i] = __builtin_nontemporal_load(&entries[blockStart + i]);

    if (t == 0) {   // (kf, chunk) step list
        int ns = 0;
        for (int kf = 0; kf < K_FILT; ++kf) {
            int c = sOff[kf + 1] - sOff[kf];
            for (int ch = 0; ch * 128 < c && ns < 96; ++ch)
                descS[ns++] = (kf << 8) | ch;
        }
        nSsh = ns;
    }
    __syncthreads();
    const int nS = nSsh;

#define LDENT(idx) ((idx) < stged ? eLds[(idx)] : entries[blockStart + (idx)])

#define STAGE(s, nb) do {                                                     \
        int d_ = descS[s];                                                    \
        int kf_ = d_ >> 8, ch_ = d_ & 255;                                    \
        int rb_ = sOff[kf_] - blockStart + ch_ * 128;                         \
        int R_  = sOff[kf_ + 1] - sOff[kf_] - ch_ * 128;                      \
        if (R_ > 128) R_ = 128;                                               \
        for (int i = w; i * 8 < R_; i += 8) {                                 \
            int rloc = i * 8 + (lane >> 3);                                   \
            int ent = LDENT(rb_ + (rloc < R_ ? rloc : R_ - 1));               \
            int gran = (lane & 7) ^ (rloc & 7);                               \
            const __bf16* src = featb + (size_t)(ent >> 7) * 64 + gran * 8;   \
            gll16(src, &Abuf[nb][i * 1024]);                                  \
        }                                                                     \
    } while (0)

    if (nS > 0) {
        STAGE(0, 0);
        __syncthreads();            // drain stage(0), make visible

        bf16x8 bfrag[4][2];
        int kfPrev = -1;
        int cur = 0;
        for (int s = 0; s < nS; ++s) {
            int d = descS[s];
            int kf = d >> 8, ch = d & 255;
            int rb = sOff[kf] - blockStart + ch * 128;
            int R  = sOff[kf + 1] - sOff[kf] - ch * 128;
            if (R > 128) R = 128;

            if (kf != kfPrev) {     // uniform branch; issued BEFORE stage so
                kfPrev = kf;        // stage stays newest in the vm FIFO
                const __bf16* wk = wtb + kf * 4096;
                #pragma unroll
                for (int n = 0; n < 4; ++n) {
                    bfrag[n][0] = *reinterpret_cast<const bf16x8*>(
                        wk + (n * 16 + lrow) * 64 + g0 * 8);
                    bfrag[n][1] = *reinterpret_cast<const bf16x8*>(
                        wk + (n * 16 + lrow) * 64 + 32 + g0 * 8);
                }
            }
            if (s + 1 < nS) STAGE(s + 1, cur ^ 1);

            // ---- compute: wave w owns group w (rows w*16..w*16+16) ----
            if (w * 16 < R) {
                int nv = R - w * 16; if (nv > 16) nv = 16;
                const char* ab = &Abuf[cur][w * 2048];
                bf16x8 a0 = *reinterpret_cast<const bf16x8*>(
                    ab + lrow * 128 + ((g0 ^ swz) * 16));
                bf16x8 a1 = *reinterpret_cast<const bf16x8*>(
                    ab + lrow * 128 + (((g0 + 4) ^ swz) * 16));
                f32x4 acc[4];
                #pragma unroll
                for (int n = 0; n < 4; ++n) {
                    acc[n] = __builtin_amdgcn_mfma_f32_16x16x32_bf16(
                        a0, bfrag[n][0], (f32x4){0.f, 0.f, 0.f, 0.f}, 0, 0, 0);
                    acc[n] = __builtin_amdgcn_mfma_f32_16x16x32_bf16(
                        a1, bfrag[n][1], acc[n], 0, 0, 0);
                }
                #pragma unroll
                for (int r = 0; r < 4; ++r) {
                    if (rg4 + r < nv) {
                        int eo = LDENT(rb + w * 16 + rg4 + r);
                        int ors = eo & 127;
                        #pragma unroll
                        for (int n = 0; n < 4; ++n)
                            atomicAdd(&outT[ors][n * 16 + lrow], acc[n][r]);
                    }
                }
            }
            __syncthreads();        // vmcnt(0) drain = next buffer staged+visible
            cur ^= 1;
        }
    }
#undef STAGE
#undef LDENT

    // ---- write out + bias ----
    const int rowBase = b * RB;
    #pragma unroll
    for (int j = 0; j < 4; ++j) {
        int idx4 = j * 512 + t;             // f32x4 index into 128x64
        int r = idx4 >> 4, c = (idx4 & 15) * 4;
        int gr = rowBase + r;
        if (gr < N_ACTIVE) {
            f32x4 bv = *reinterpret_cast<const f32x4*>(&bias[c]);
            f32x4 v  = *reinterpret_cast<const f32x4*>(&outT[r][c]);
            v += bv;
            __builtin_nontemporal_store(v, reinterpret_cast<f32x4*>(&out[gr * 64 + c]));
        }
    }
}

extern "C" void kernel_launch(void* const* d_in, const int* in_sizes, int n_in,
                              void* d_out, int out_size, void* d_ws, size_t ws_size,
                              hipStream_t stream) {
    const float* feat    = (const float*)d_in[0];
    const float* weight  = (const float*)d_in[1];
    const float* bias    = (const float*)d_in[2];
    const int*   in_idx  = (const int*)d_in[3];
    const int*   out_idx = (const int*)d_in[4];
    float* out = (float*)d_out;

    char* wsb = (char*)d_ws;
    __bf16* featb = (__bf16*)wsb;                               // 25,600,000 B
    __bf16* wtb   = (__bf16*)(wsb + 25600000);                  //    221,184 B
    int* cnt      = (int*)(wsb + 25600000 + 221184);
    int* cursor   = cnt + NBUCK;
    int* off      = cursor + NBUCK;                             // NBUCK+1
    int* bsum     = off + NBUCK + 1;                            // NSB
    int* entries  = bsum + NSB;                                 // TOTP

    zero_ints<<<dim3((NBUCK + 255) / 256), dim3(256), 0, stream>>>(cnt, NBUCK);
    prep_fused<<<dim3(CF_BLOCKS + CW_BLOCKS + HI_BLOCKS), dim3(256), 0, stream>>>(
        feat, featb, weight, wtb, out_idx, cnt);
    scan1<<<dim3(NSB), dim3(256), 0, stream>>>(cnt, off, bsum);
    scan2<<<dim3(1), dim3(256), 0, stream>>>(bsum);
    scan3<<<dim3(NSB), dim3(256), 0, stream>>>(off, bsum, cursor);
    scatter_pack<<<dim3((TOTP + 255) / 256), dim3(256), 0, stream>>>(in_idx, out_idx, cursor, entries);
    conv_fused<<<dim3(NB), dim3(512), 0, stream>>>(featb, wtb, bias, off, entries, out);
}

// Round 9
// 1344.399 us; speedup vs baseline: 1.0825x; 1.0825x over previous
//
#include <hip/hip_runtime.h>
#include <stdint.h>

#define N_ACTIVE 200000
#define N_IN 64
#define N_OUT 64
#define K_FILT 27
#define R_PAIRS 100000
#define TOTP (K_FILT * R_PAIRS)          // 2,700,000
#define RB 128                           // output rows per block
#define NB ((N_ACTIVE + RB - 1) / RB)    // 1563
#define NBUCK (NB * K_FILT)              // 42,201
#define ELDS 2304
#define MAXG 256

#define CF_BLOCKS (N_ACTIVE * N_IN / 8 / 256)    // 6250
#define CW_BLOCKS K_FILT
#define HI_BLOCKS ((TOTP + 255) / 256)

typedef __bf16 bf16x8 __attribute__((ext_vector_type(8)));
typedef float f32x4 __attribute__((ext_vector_type(4)));

__global__ __launch_bounds__(256) void zero_ints(int* __restrict__ p, int n) {
    int i = blockIdx.x * 256 + threadIdx.x;
    if (i < n) p[i] = 0;
}

// ---------------------------------------------------------------------------
// fused prep: convert_feat | convert_wt | dual histogram (out-bucket, in-row)
// ---------------------------------------------------------------------------
__global__ __launch_bounds__(256) void prep_fused(
    const float* __restrict__ feat, __bf16* __restrict__ featb,
    const float* __restrict__ wsrc, __bf16* __restrict__ wt,
    const int* __restrict__ out_idx, const int* __restrict__ in_idx,
    int* __restrict__ cntO, int* __restrict__ cntI)
{
    int bb = blockIdx.x, t = threadIdx.x;
    if (bb < CF_BLOCKS) {
        int i = bb * 256 + t;
        const f32x4* src = reinterpret_cast<const f32x4*>(feat) + 2 * (size_t)i;
        f32x4 v0 = __builtin_nontemporal_load(src);
        f32x4 v1 = __builtin_nontemporal_load(src + 1);
        bf16x8 o;
        o[0] = (__bf16)v0[0]; o[1] = (__bf16)v0[1]; o[2] = (__bf16)v0[2]; o[3] = (__bf16)v0[3];
        o[4] = (__bf16)v1[0]; o[5] = (__bf16)v1[1]; o[6] = (__bf16)v1[2]; o[7] = (__bf16)v1[3];
        reinterpret_cast<bf16x8*>(featb)[i] = o;
    } else if (bb < CF_BLOCKS + CW_BLOCKS) {
        int kf = bb - CF_BLOCKS;
        const float* wk = wsrc + kf * 4096;
        __bf16* wo = wt + kf * 4096;
        int o = t >> 2, i0 = (t & 3) * 16;
        bf16x8 a, b;
        #pragma unroll
        for (int j = 0; j < 8; ++j) a[j] = (__bf16)wk[(i0 + j) * 64 + o];
        #pragma unroll
        for (int j = 0; j < 8; ++j) b[j] = (__bf16)wk[(i0 + 8 + j) * 64 + o];
        *reinterpret_cast<bf16x8*>(wo + o * 64 + i0) = a;
        *reinterpret_cast<bf16x8*>(wo + o * 64 + i0 + 8) = b;
    } else {
        int p = (bb - CF_BLOCKS - CW_BLOCKS) * 256 + t;
        if (p < TOTP) {
            unsigned k = (unsigned)p / (unsigned)R_PAIRS;
            int b = (out_idx[p] >> 7) * K_FILT + (int)k;
            atomicAdd(&cntO[b], 1);
            if (cntI) atomicAdd(&cntI[in_idx[p]], 1);
        }
    }
}

// ---- generic 2-level exclusive scan (1024 elems per block, 4/thread) ----
__global__ __launch_bounds__(256) void scanA(const int* __restrict__ cnt,
                                             int* __restrict__ off,
                                             int* __restrict__ bsum, int n) {
    __shared__ int s[256];
    int t = threadIdx.x, base = blockIdx.x * 1024 + t * 4;
    int v[4], sum = 0;
    #pragma unroll
    for (int j = 0; j < 4; ++j) { v[j] = (base + j < n) ? cnt[base + j] : 0; sum += v[j]; }
    s[t] = sum;
    __syncthreads();
    #pragma unroll
    for (int d = 1; d < 256; d <<= 1) {
        int x = (t >= d) ? s[t - d] : 0;
        __syncthreads();
        s[t] += x;
        __syncthreads();
    }
    int run = s[t] - sum;
    #pragma unroll
    for (int j = 0; j < 4; ++j) { if (base + j < n) off[base + j] = run; run += v[j]; }
    if (t == 255) bsum[blockIdx.x] = s[255];
}

__global__ __launch_bounds__(256) void scanB(int* __restrict__ bsum, int nb) {
    __shared__ int s[256];
    int t = threadIdx.x;
    int v = (t < nb) ? bsum[t] : 0;
    s[t] = v;
    __syncthreads();
    #pragma unroll
    for (int d = 1; d < 256; d <<= 1) {
        int x = (t >= d) ? s[t - d] : 0;
        __syncthreads();
        s[t] += x;
        __syncthreads();
    }
    if (t < nb) bsum[t] = s[t] - v;
}

__global__ __launch_bounds__(256) void scanC(int* __restrict__ off,
                                             const int* __restrict__ bsum,
                                             int* __restrict__ cursor,
                                             int n, int total) {
    int base = blockIdx.x * 1024 + threadIdx.x * 4;
    int add = bsum[blockIdx.x];
    #pragma unroll
    for (int j = 0; j < 4; ++j) {
        int i = base + j;
        if (i < n) { int v = off[i] + add; off[i] = v; cursor[i] = v; }
    }
    if (base == 0) off[n] = total;
}

// ---------------------------------------------------------------------------
// scatter: out-sorted entries + in-sorted destination list (iEnt[j] = G pos)
// entry packed (in_row << 7) | out_local
// ---------------------------------------------------------------------------
__global__ __launch_bounds__(256) void scatter_pack(const int* __restrict__ in_idx,
                                                    const int* __restrict__ out_idx,
                                                    int* __restrict__ cursO,
                                                    int* __restrict__ entries,
                                                    int* __restrict__ cursI,
                                                    int* __restrict__ iEnt) {
    int p = blockIdx.x * 256 + threadIdx.x;
    if (p >= TOTP) return;
    unsigned k = (unsigned)p / (unsigned)R_PAIRS;
    int orow = out_idx[p];
    int iv = in_idx[p];
    int bkt = (orow >> 7) * K_FILT + (int)k;
    int pos = atomicAdd(&cursO[bkt], 1);
    entries[pos] = (iv << 7) | (orow & 127);
    if (iEnt) {
        int jpos = atomicAdd(&cursI[iv], 1);
        iEnt[jpos] = pos;
    }
}

// ---------------------------------------------------------------------------
// phase 1': stream featb rows sequentially, scatter each to its G positions.
// 8 lanes per row (16 B each); writes are contiguous-128B fire-and-forget.
// ---------------------------------------------------------------------------
__global__ __launch_bounds__(256) void gatherG(const __bf16* __restrict__ featb,
                                               const int* __restrict__ offI,
                                               const int* __restrict__ iEnt,
                                               __bf16* __restrict__ G) {
    int t = threadIdx.x;
    int row = blockIdx.x * 32 + (t >> 3);
    int q = t & 7;
    if (row >= N_ACTIVE) return;
    bf16x8 v = *reinterpret_cast<const bf16x8*>(featb + (size_t)row * 64 + q * 8);
    int r0 = offI[row], r1 = offI[row + 1];
    for (int d = r0; d < r1; ++d) {
        int dst = iEnt[d];
        __builtin_nontemporal_store(v,
            reinterpret_cast<bf16x8*>(G + (size_t)dst * 64 + q * 8));
    }
}

// ---------------------------------------------------------------------------
// phase 2: block owns 128 out rows = a CONTIGUOUS slice of G. Flat group
// descriptors; waves stride groups. A-frags stream from G (useG=1) or gather
// from featb (fallback). MFMA layouts as r3 (verified): A row=lane&15,
// k=(lane>>4)*8; C/D col=lane&15,row=(lane>>4)*4+reg. LDS ds_add scatter.
// ---------------------------------------------------------------------------
__global__ __launch_bounds__(256) void conv_dense(
    const __bf16* __restrict__ featb,
    const __bf16* __restrict__ G,
    const __bf16* __restrict__ wtb,
    const float* __restrict__ bias,
    const int* __restrict__ off,        // [NBUCK+1]
    const int* __restrict__ entries,    // [TOTP] packed
    float* __restrict__ out,
    int useG)
{
    __shared__ float outT[RB][68];      // 34,816 B
    __shared__ int   eLds[ELDS];        //  9,216 B
    __shared__ int   sOff[K_FILT + 1];
    __shared__ int   descLds[MAXG];
    __shared__ int   gc[32];
    __shared__ int   gCount;

    const int b = blockIdx.x;
    const int t = threadIdx.x;
    const int w = t >> 6;
    const int lane = t & 63;
    const int lrow = lane & 15;
    const int lkB  = (lane >> 4) * 8;
    const int rg4  = (lane >> 4) * 4;
    const int bK = b * K_FILT;

    if (t < K_FILT + 1) sOff[t] = off[bK + t];
    {
        f32x4 z = {0.f, 0.f, 0.f, 0.f};
        f32x4* o4 = reinterpret_cast<f32x4*>(&outT[0][0]);
        for (int j = t; j < RB * 68 / 4; j += 256) o4[j] = z;
    }
    __syncthreads();

    const int blockStart = sOff[0];
    const int total = sOff[K_FILT] - blockStart;
    const int stged = total < ELDS ? total : ELDS;
    for (int i = t; i < stged; i += 256)
        eLds[i] = __builtin_nontemporal_load(&entries[blockStart + i]);

    // parallel descriptor build: (kf<<18 | startJ<<5 | nvalid)
    if (t < K_FILT) gc[t] = (sOff[t + 1] - sOff[t] + 15) >> 4;
    __syncthreads();
    if (t == 0) {
        int s = 0;
        #pragma unroll
        for (int kf = 0; kf < K_FILT; ++kf) { int g = gc[kf]; gc[kf] = s; s += g; }
        gCount = s;
    }
    __syncthreads();
    if (t < K_FILT) {
        int base = sOff[t] - blockStart;
        int c = sOff[t + 1] - sOff[t];
        int s = gc[t];
        for (int j = 0, g = 0; j < c; j += 16, ++g) {
            int nv = c - j; if (nv > 16) nv = 16;
            descLds[s + g] = (t << 18) | ((base + j) << 5) | nv;
        }
    }
    __syncthreads();

    const int nG = gCount;
    int curKf = -1;
    bf16x8 bfrag[4][2];

#define LDENT(idx) ((idx) < stged ? eLds[(idx)] : entries[blockStart + (idx)])

    for (int g = w; g < nG; g += 4) {
        int d = descLds[g];
        int kf = d >> 18, sj = (d >> 5) & 0x1FFF, nv = d & 31;
        if (kf != curKf) {
            curKf = kf;
            const __bf16* wk = wtb + kf * 4096;
            #pragma unroll
            for (int n = 0; n < 4; ++n) {
                bfrag[n][0] = *reinterpret_cast<const bf16x8*>(
                    wk + (n * 16 + lrow) * 64 + lkB);
                bfrag[n][1] = *reinterpret_cast<const bf16x8*>(
                    wk + (n * 16 + lrow) * 64 + 32 + lkB);
            }
        }
        int ja = sj + (lrow < nv ? lrow : 0);
        bf16x8 a0, a1;
        if (useG) {
            const __bf16* ap = G + (size_t)(blockStart + ja) * 64 + lkB;
            a0 = *reinterpret_cast<const bf16x8*>(ap);
            a1 = *reinterpret_cast<const bf16x8*>(ap + 32);
        } else {
            int e = LDENT(ja);
            const __bf16* ap = featb + (size_t)(e >> 7) * 64 + lkB;
            a0 = *reinterpret_cast<const bf16x8*>(ap);
            a1 = *reinterpret_cast<const bf16x8*>(ap + 32);
        }

        f32x4 acc[4];
        #pragma unroll
        for (int n = 0; n < 4; ++n) {
            acc[n] = __builtin_amdgcn_mfma_f32_16x16x32_bf16(
                a0, bfrag[n][0], (f32x4){0.f, 0.f, 0.f, 0.f}, 0, 0, 0);
            acc[n] = __builtin_amdgcn_mfma_f32_16x16x32_bf16(
                a1, bfrag[n][1], acc[n], 0, 0, 0);
        }
        #pragma unroll
        for (int r = 0; r < 4; ++r) {
            if (rg4 + r < nv) {
                int eo = LDENT(sj + rg4 + r);
                int ors = eo & 127;
                #pragma unroll
                for (int n = 0; n < 4; ++n)
                    atomicAdd(&outT[ors][n * 16 + lrow], acc[n][r]);
            }
        }
    }
#undef LDENT

    __syncthreads();
    const int rowBase = b * RB;
    for (int j = t; j < RB * 64 / 4; j += 256) {
        int r = j >> 4, c = (j & 15) * 4;
        int gr = rowBase + r;
        if (gr < N_ACTIVE) {
            f32x4 bv = *reinterpret_cast<const f32x4*>(&bias[c]);
            f32x4 v  = *reinterpret_cast<const f32x4*>(&outT[r][c]);
            v += bv;
            __builtin_nontemporal_store(v, reinterpret_cast<f32x4*>(&out[gr * 64 + c]));
        }
    }
}

extern "C" void kernel_launch(void* const* d_in, const int* in_sizes, int n_in,
                              void* d_out, int out_size, void* d_ws, size_t ws_size,
                              hipStream_t stream) {
    const float* feat    = (const float*)d_in[0];
    const float* weight  = (const float*)d_in[1];
    const float* bias    = (const float*)d_in[2];
    const int*   in_idx  = (const int*)d_in[3];
    const int*   out_idx = (const int*)d_in[4];
    float* out = (float*)d_out;

    // ---- workspace layout ----
    const size_t G_BYTES    = (size_t)TOTP * 64 * 2;          // 345,600,000
    const size_t FB_BYTES   = (size_t)N_ACTIVE * 64 * 2;      //  25,600,000
    const size_t WT_BYTES   = (size_t)K_FILT * 4096 * 2;      //     221,184
    const size_t INT_COUNT  = (size_t)NBUCK + N_ACTIVE        // cntO, cntI
                            + NBUCK + N_ACTIVE                // cursO, cursI
                            + (NBUCK + 1) + (N_ACTIVE + 1)    // offO, offI
                            + 256 + 256                       // bsumO, bsumI
                            + (size_t)TOTP + (size_t)TOTP;    // entries, iEnt
    const size_t NEED_A = G_BYTES + FB_BYTES + WT_BYTES + INT_COUNT * 4;
    const int useG = (ws_size >= NEED_A) ? 1 : 0;

    char* wsb = (char*)d_ws;
    __bf16* G = (__bf16*)wsb;
    size_t base = useG ? G_BYTES : 0;
    __bf16* featb = (__bf16*)(wsb + base);
    __bf16* wtb   = (__bf16*)(wsb + base + FB_BYTES);
    int* ip       = (int*)(wsb + base + FB_BYTES + WT_BYTES);
    int* cntO = ip;                      ip += NBUCK;
    int* cntI = ip;                      ip += N_ACTIVE;
    int* cursO = ip;                     ip += NBUCK;
    int* cursI = ip;                     ip += N_ACTIVE;
    int* offO = ip;                      ip += NBUCK + 1;
    int* offI = ip;                      ip += N_ACTIVE + 1;
    int* bsumO = ip;                     ip += 256;
    int* bsumI = ip;                     ip += 256;
    int* entries = ip;                   ip += TOTP;
    int* iEnt = ip;

    const int NSB_O = (NBUCK + 1023) / 1024;       // 42
    const int NSB_I = (N_ACTIVE + 1023) / 1024;    // 196

    // zero both histograms (contiguous)
    zero_ints<<<dim3((NBUCK + N_ACTIVE + 255) / 256), dim3(256), 0, stream>>>(
        cntO, NBUCK + N_ACTIVE);
    prep_fused<<<dim3(CF_BLOCKS + CW_BLOCKS + HI_BLOCKS), dim3(256), 0, stream>>>(
        feat, featb, weight, wtb, out_idx, in_idx, cntO, useG ? cntI : nullptr);

    scanA<<<dim3(NSB_O), dim3(256), 0, stream>>>(cntO, offO, bsumO, NBUCK);
    scanB<<<dim3(1), dim3(256), 0, stream>>>(bsumO, NSB_O);
    scanC<<<dim3(NSB_O), dim3(256), 0, stream>>>(offO, bsumO, cursO, NBUCK, TOTP);

    if (useG) {
        scanA<<<dim3(NSB_I), dim3(256), 0, stream>>>(cntI, offI, bsumI, N_ACTIVE);
        scanB<<<dim3(1), dim3(256), 0, stream>>>(bsumI, NSB_I);
        scanC<<<dim3(NSB_I), dim3(256), 0, stream>>>(offI, bsumI, cursI, N_ACTIVE, TOTP);
    }

    scatter_pack<<<dim3((TOTP + 255) / 256), dim3(256), 0, stream>>>(
        in_idx, out_idx, cursO, entries, useG ? cursI : nullptr, useG ? iEnt : nullptr);

    if (useG)
        gatherG<<<dim3((N_ACTIVE + 31) / 32), dim3(256), 0, stream>>>(featb, offI, iEnt, G);

    conv_dense<<<dim3(NB), dim3(256), 0, stream>>>(featb, G, wtb, bias, offO, entries,
                                                   out, useG);
}